// Round 20
// baseline (100.618 us; speedup 1.0000x reference)
//
#include <hip/hip_runtime.h>
#include <hip/hip_bf16.h>

#define B_ 8
#define S_ 2048
#define F_ 1024
#define DK_ 128
#define M_ (B_*S_)          // 16384

typedef unsigned short u16;
typedef short short8 __attribute__((ext_vector_type(8)));
typedef float f32x4 __attribute__((ext_vector_type(4)));
typedef float f32x16 __attribute__((ext_vector_type(16)));

__device__ __forceinline__ u16 f2bf(float f) {
    unsigned int u = __float_as_uint(f);
    u += 0x7FFFu + ((u >> 16) & 1u);    // round-to-nearest-even
    return (u16)(u >> 16);
}
__device__ __forceinline__ unsigned int pack2(float a, float b) {
    return (unsigned int)f2bf(a) | ((unsigned int)f2bf(b) << 16);
}
__device__ __forceinline__ float fexp2(float x) {
#if __has_builtin(__builtin_amdgcn_exp2f)
    return __builtin_amdgcn_exp2f(x);   // raw v_exp_f32 (2^x)
#else
    return exp2f(x);
#endif
}
__device__ __forceinline__ unsigned int cvt_pk_bf16(float lo, float hi) {
    unsigned int r;
    asm("v_cvt_pk_bf16_f32 %0, %1, %2" : "=v"(r) : "v"(lo), "v"(hi));
    return r;
}
// v_permlane32_swap_b32 a, b:  a_hi <-> b_lo.
__device__ __forceinline__ void pl32_swap(unsigned int& a, unsigned int& b) {
    asm("v_permlane32_swap_b32 %0, %1" : "+v"(a), "+v"(b));
}

// ---------------------------------------------------------------------------
// Kernel 1: W [1024][128] fp32 -> WT [3][128][1024] bf16 (transposed).
// w_q gets (1/sqrt(128)) * log2(e) folded in, so softmax uses raw exp2.
// ---------------------------------------------------------------------------
__global__ __launch_bounds__(256) void prep_wt(const float* __restrict__ wq,
                                               const float* __restrict__ wk,
                                               const float* __restrict__ wv,
                                               u16* __restrict__ WT) {
    int id = blockIdx.x * 256 + threadIdx.x;
    if (id >= 3 * DK_ * F_) return;
    int m   = id / (DK_ * F_);
    int rem = id - m * (DK_ * F_);
    int c   = rem / F_;
    int k   = rem - c * F_;
    const float* w = (m == 0) ? wq : (m == 1) ? wk : wv;
    float v = w[k * DK_ + c];
    if (m == 0) v *= 0.12751741951f;   // (1/sqrt(128)) * log2(e)
    WT[id] = f2bf(v);
}

// ---------------------------------------------------------------------------
// Kernel 2: projection GEMM v2.1 — R19 with the W-staging bug fixed.
// R19 FAILED (absmax 10.4): W tile at BK=64 is [128 cols][64 u16] = 64B =
// FOUR int4 per thread, but LOADS/WRITES moved only wv0,wv1 (32B) — columns
// wk_+16..+31 of every tile were stale.  v2.1 loads/writes wv0..wv3.
// Structure otherwise identical: BK=64 (32 barriers vs old 64), T14
// issue-early/write-late, fragment-layout epilogue, bitwise-same f2bf.
// ---------------------------------------------------------------------------
__global__ __launch_bounds__(256, 3) void proj(const float* __restrict__ xq,
                                               const float* __restrict__ xk,
                                               const float* __restrict__ xv,
                                               const u16* __restrict__ WT,
                                               u16* __restrict__ qfr,
                                               u16* __restrict__ kfr,
                                               u16* __restrict__ vfr) {
    const int mode = blockIdx.y;
    const float* X = (mode == 0) ? xq : (mode == 1) ? xk : xv;
    const u16*   W = WT + mode * (DK_ * F_);

    __shared__ u16 a_lds[64][72];    // 72 u16 = 144B stride: rows 2-way max (free)
    __shared__ u16 w_lds[128][72];

    const int t    = threadIdx.x;
    const int lane = t & 63;
    const int wv_  = t >> 6;
    const int l15  = lane & 15, l4 = lane >> 4;
    const int row0 = blockIdx.x * 64;

    // staging mappings (BK=64):
    //   A: thread t -> row ar = t>>2 (0..63), kseg ak = (t&3)*16  (16 fp32 -> 16 bf16)
    //   W: thread t -> col wc = t>>1 (0..127), kseg wk_ = (t&1)*32 (32 bf16 = 4 int4)
    const int ar = t >> 2, ak = (t & 3) * 16;
    const int wc = t >> 1, wk_ = (t & 1) * 32;

    float4 ax0, ax1, ax2, ax3;       // 16 fp32 of X
    int4   wv0, wv1, wv2, wv3;       // 32 bf16 of W

#define LOADS(k0)                                                              \
    {                                                                          \
        const float4* asrc = (const float4*)(X + (size_t)(row0 + ar) * F_ + (k0) + ak); \
        ax0 = asrc[0]; ax1 = asrc[1]; ax2 = asrc[2]; ax3 = asrc[3];            \
        const int4* wsrc = (const int4*)(W + (size_t)wc * F_ + (k0) + wk_);    \
        wv0 = wsrc[0]; wv1 = wsrc[1]; wv2 = wsrc[2]; wv3 = wsrc[3];            \
    }
#define WRITES()                                                               \
    {                                                                          \
        int4 o0, o1;                                                           \
        o0.x = pack2(ax0.x, ax0.y); o0.y = pack2(ax0.z, ax0.w);                \
        o0.z = pack2(ax1.x, ax1.y); o0.w = pack2(ax1.z, ax1.w);                \
        o1.x = pack2(ax2.x, ax2.y); o1.y = pack2(ax2.z, ax2.w);                \
        o1.z = pack2(ax3.x, ax3.y); o1.w = pack2(ax3.z, ax3.w);                \
        *(int4*)&a_lds[ar][ak]      = o0;                                      \
        *(int4*)&a_lds[ar][ak + 8]  = o1;                                      \
        *(int4*)&w_lds[wc][wk_]      = wv0;                                    \
        *(int4*)&w_lds[wc][wk_ + 8]  = wv1;                                    \
        *(int4*)&w_lds[wc][wk_ + 16] = wv2;                                    \
        *(int4*)&w_lds[wc][wk_ + 24] = wv3;                                    \
    }

    f32x4 acc[8];
#pragma unroll
    for (int j = 0; j < 8; ++j) acc[j] = f32x4{0.f, 0.f, 0.f, 0.f};

    LOADS(0);
    WRITES();

    for (int ks = 0; ks < 16; ++ks) {
        __syncthreads();                       // staged data visible

        if (ks < 15) LOADS((ks + 1) * 64);     // next-step loads fly under MFMA

        short8 af[2], bf[8][2];
#pragma unroll
        for (int kc = 0; kc < 2; ++kc)
            af[kc] = *(const short8*)&a_lds[wv_ * 16 + l15][kc * 32 + l4 * 8];
#pragma unroll
        for (int ct = 0; ct < 8; ++ct)
#pragma unroll
            for (int kc = 0; kc < 2; ++kc)
                bf[ct][kc] = *(const short8*)&w_lds[ct * 16 + l15][kc * 32 + l4 * 8];

        if (mode < 2) {
#pragma unroll
            for (int kc = 0; kc < 2; ++kc)
#pragma unroll
                for (int ct = 0; ct < 8; ++ct)
                    acc[ct] = __builtin_amdgcn_mfma_f32_16x16x32_bf16(
                        af[kc], bf[ct][kc], acc[ct], 0, 0, 0);
        } else {
#pragma unroll
            for (int kc = 0; kc < 2; ++kc)
#pragma unroll
                for (int ct = 0; ct < 8; ++ct)
                    acc[ct] = __builtin_amdgcn_mfma_f32_16x16x32_bf16(
                        bf[ct][kc], af[kc], acc[ct], 0, 0, 0);
        }
        __syncthreads();                       // all reads done

        if (ks < 15) WRITES();                 // cvt + ds_write (drains under next barrier)
    }
#undef LOADS
#undef WRITES

    if (mode < 2) {
        u16* OUT = (mode == 0) ? qfr : kfr;
#pragma unroll
        for (int ct = 0; ct < 8; ++ct)
#pragma unroll
            for (int r = 0; r < 4; ++r) {
                int q = row0 + wv_ * 16 + l4 * 4 + r;     // row (q or kv)
                int d = ct * 16 + l15;                    // col
                int g = q >> 5, j = q & 31;
                int c = d >> 4, h2 = (d >> 3) & 1, e = d & 7;
                OUT[(((size_t)g * 8 + c) * 64 + h2 * 32 + j) * 8 + e] = f2bf(acc[ct][r]);
            }
    } else {
#pragma unroll
        for (int ct = 0; ct < 8; ++ct)
#pragma unroll
            for (int r = 0; r < 4; ++r) {
                int d = ct * 16 + l4 * 4 + r;             // C row = W col = d
                int m = row0 + wv_ * 16 + l15;            // C col = kv
                int g = m >> 5, ch = (m >> 4) & 1, h2 = (m >> 3) & 1, e = m & 7;
                int ct2 = d >> 5, l31 = d & 31;
                vfr[((((size_t)g * 4 + ct2) * 2 + ch) * 64 + h2 * 32 + l31) * 8 + e]
                    = f2bf(acc[ct][r]);
            }
    }
}

// ---------------------------------------------------------------------------
// Kernel 3: flash attention v7 (byte-identical to R17; ~26us measured R18).
// ---------------------------------------------------------------------------
__global__ __launch_bounds__(512)
__attribute__((amdgpu_waves_per_eu(2)))
void attn(const u16* __restrict__ qfr,
          const u16* __restrict__ kfr,
          const u16* __restrict__ vfr,
          float* __restrict__ out) {
    __shared__ float ob[64][132];
    __shared__ float m_l[2][4][32], l_l[2][4][2][32], gm_l[2][32], gl_l[2][32];

    const int t      = threadIdx.x;
    const int lane   = t & 63;
    const int wv_    = t >> 6;              // 0..7
    const int q_sub  = wv_ & 1;
    const int kv_sub = wv_ >> 1;            // 0..3
    const int r31    = lane & 31;
    const int hi     = lane >> 5;

    const int b  = blockIdx.x & 7;
    const int qi = blockIdx.x >> 3;          // 0..31
    const int qrow0 = b * S_ + qi * 64;

    // Q fragments (coalesced: 1KB per instr)
    const size_t qg = (size_t)(b * 64 + qi * 2 + q_sub);
    short8 qf[8];
#pragma unroll
    for (int c = 0; c < 8; ++c)
        qf[c] = *(const short8*)(qfr + (qg * 8 + c) * 512 + lane * 8);

    f32x16 o4[4];
#pragma unroll
    for (int ct = 0; ct < 4; ++ct)
#pragma unroll
        for (int i = 0; i < 16; ++i) o4[ct][i] = 0.f;
    float mrun = -1.0e30f, lrun = 0.f;      // mrun cross-half uniform; lrun per-half

    // prologue: K fragments for kt=0
    short8 kf[8];
    {
        const size_t g0 = (size_t)(b * 64 + kv_sub);
#pragma unroll
        for (int c = 0; c < 8; ++c)
            kf[c] = *(const short8*)(kfr + (g0 * 8 + c) * 512 + lane * 8);
    }

    for (int kt = 0; kt < 16; ++kt) {
        const size_t g = (size_t)(b * 64 + kt * 4 + kv_sub);

        // ---- QK^T (own quarter), two independent 4-chains then add
        f32x16 sa, sb;
#pragma unroll
        for (int i = 0; i < 16; ++i) { sa[i] = 0.f; sb[i] = 0.f; }
#pragma unroll
        for (int c = 0; c < 4; ++c) {
            sa = __builtin_amdgcn_mfma_f32_32x32x16_bf16(kf[c],     qf[c],     sa, 0, 0, 0);
            sb = __builtin_amdgcn_mfma_f32_32x32x16_bf16(kf[c + 4], qf[c + 4], sb, 0, 0, 0);
        }
        f32x16 st;
#pragma unroll
        for (int i = 0; i < 16; ++i) st[i] = sa[i] + sb[i];

        // ---- V fragments issued now; land under softmax (coalesced dwordx4)
        short8 vf[4][2];
#pragma unroll
        for (int ct = 0; ct < 4; ++ct)
#pragma unroll
            for (int ch = 0; ch < 2; ++ch)
                vf[ct][ch] = *(const short8*)(vfr + (((g * 4 + ct) * 2 + ch) * 64 + lane) * 8);

        // ---- per-lane softmax (log2 units), cross-lane only in rare defer path
        float tm = st[0];
#pragma unroll
        for (int i = 1; i < 16; ++i) tm = fmaxf(tm, st[i]);
        if (__any(tm > mrun + 8.0f)) {
            tm = fmaxf(tm, __shfl_xor(tm, 32, 64));   // make mrun half-uniform
            float mn = fmaxf(mrun, tm);
            float fs = fexp2(mrun - mn);
            mrun = mn;
            lrun *= fs;
#pragma unroll
            for (int ct = 0; ct < 4; ++ct)
#pragma unroll
                for (int i = 0; i < 16; ++i) o4[ct][i] *= fs;
        }
        float s0 = 0.f, s1 = 0.f;
#pragma unroll
        for (int i = 0; i < 16; i += 2) {
            st[i]     = fexp2(st[i] - mrun);
            st[i + 1] = fexp2(st[i + 1] - mrun);
            s0 += st[i]; s1 += st[i + 1];
        }
        lrun += s0 + s1;

        // ---- P -> bf16 B-fragments via permlane32_swap
        short8 bp[2];
#pragma unroll
        for (int ch = 0; ch < 2; ++ch) {
            unsigned int A1 = cvt_pk_bf16(st[ch * 8 + 0], st[ch * 8 + 1]);
            unsigned int A2 = cvt_pk_bf16(st[ch * 8 + 2], st[ch * 8 + 3]);
            unsigned int A3 = cvt_pk_bf16(st[ch * 8 + 4], st[ch * 8 + 5]);
            unsigned int A4 = cvt_pk_bf16(st[ch * 8 + 6], st[ch * 8 + 7]);
            pl32_swap(A1, A3);
            pl32_swap(A2, A4);
            int4 w;
            w.x = (int)A1; w.y = (int)A2; w.z = (int)A3; w.w = (int)A4;
            bp[ch] = *(short8*)&w;
        }

        // ---- prefetch next K fragments (kf regs free); land under PV
        if (kt < 15) {
            const size_t gn = (size_t)(b * 64 + (kt + 1) * 4 + kv_sub);
#pragma unroll
            for (int c = 0; c < 8; ++c)
                kf[c] = *(const short8*)(kfr + (gn * 8 + c) * 512 + lane * 8);
        }

        // ---- PV: full d per wave, k-dim = this wave's 32-kv slice
#pragma unroll
        for (int ct = 0; ct < 4; ++ct) {
            o4[ct] = __builtin_amdgcn_mfma_f32_32x32x16_bf16(vf[ct][0], bp[0], o4[ct], 0, 0, 0);
            o4[ct] = __builtin_amdgcn_mfma_f32_32x32x16_bf16(vf[ct][1], bp[1], o4[ct], 0, 0, 0);
        }
    }

    // ---- epilogue: combine 4 kv_sub partials per q_sub ----
    __syncthreads();
    l_l[q_sub][kv_sub][hi][r31] = lrun;
    if (lane < 32) m_l[q_sub][kv_sub][r31] = mrun;
    __syncthreads();
    if (t < 64) {
        int qs = t >> 5, qq = t & 31;
        float gm = -1.0e30f;
#pragma unroll
        for (int ks = 0; ks < 4; ++ks) gm = fmaxf(gm, m_l[qs][ks][qq]);
        float gl = 0.f;
#pragma unroll
        for (int ks = 0; ks < 4; ++ks)
            gl += (l_l[qs][ks][0][qq] + l_l[qs][ks][1][qq]) * fexp2(m_l[qs][ks][qq] - gm);
        gm_l[qs][qq] = gm;
        gl_l[qs][qq] = gl;
    }
    __syncthreads();

    const float sc = fexp2(mrun - gm_l[q_sub][r31]);
    const int qrow = q_sub * 32 + r31;
    for (int rr = 0; rr < 4; ++rr) {
        if (kv_sub == rr) {
            if (rr == 0) {
#pragma unroll
                for (int ct = 0; ct < 4; ++ct)
#pragma unroll
                    for (int i = 0; i < 16; ++i) {
                        int d = ct * 32 + (i & 3) + 8 * (i >> 2) + 4 * hi;
                        ob[qrow][d] = o4[ct][i] * sc;
                    }
            } else {
#pragma unroll
                for (int ct = 0; ct < 4; ++ct)
#pragma unroll
                    for (int i = 0; i < 16; ++i) {
                        int d = ct * 32 + (i & 3) + 8 * (i >> 2) + 4 * hi;
                        ob[qrow][d] += o4[ct][i] * sc;
                    }
            }
        }
        __syncthreads();
    }

    // ---- final store: thread t -> row t>>3 (0..63), cols (t&7)*16..+16
    {
        int row = t >> 3, d0 = (t & 7) * 16;
        float inv = 1.0f / gl_l[row >> 5][row & 31];
        float* dst = out + (size_t)(qrow0 + row) * DK_ + d0;
#pragma unroll
        for (int j = 0; j < 16; j += 4) {
            float4 v;
            v.x = ob[row][d0 + j]     * inv;
            v.y = ob[row][d0 + j + 1] * inv;
            v.z = ob[row][d0 + j + 2] * inv;
            v.w = ob[row][d0 + j + 3] * inv;
            *(float4*)(dst + j) = v;
        }
    }
}

// ---------------------------------------------------------------------------
extern "C" void kernel_launch(void* const* d_in, const int* in_sizes, int n_in,
                              void* d_out, int out_size, void* d_ws, size_t ws_size,
                              hipStream_t stream) {
    const float* q  = (const float*)d_in[0];
    const float* k  = (const float*)d_in[1];
    const float* v  = (const float*)d_in[2];
    const float* wq = (const float*)d_in[3];
    const float* wk = (const float*)d_in[4];
    const float* wv = (const float*)d_in[5];
    float* out = (float*)d_out;

    char* ws = (char*)d_ws;
    u16* WT  = (u16*)ws;                                   // 786432 B
    u16* qfr = (u16*)(ws + 786432);                        // 4 MB (fragment layout)
    u16* kfr = (u16*)(ws + 786432 + 4194304);              // 4 MB
    u16* vfr = (u16*)(ws + 786432 + 2 * 4194304);          // 4 MB

    prep_wt<<<dim3(1536), dim3(256), 0, stream>>>(wq, wk, wv, WT);
    proj<<<dim3(256, 3), dim3(256), 0, stream>>>(q, k, v, WT, qfr, kfr, vfr);
    attn<<<dim3(256), dim3(512), 0, stream>>>(qfr, kfr, vfr, out);
}

// Round 21
// 74.271 us; speedup vs baseline: 1.3547x; 1.3547x over previous
//
#include <hip/hip_runtime.h>
#include <hip/hip_bf16.h>

#define B_ 8
#define S_ 2048
#define F_ 1024
#define DK_ 128
#define M_ (B_*S_)          // 16384

typedef unsigned short u16;
typedef short short8 __attribute__((ext_vector_type(8)));
typedef float f32x4 __attribute__((ext_vector_type(4)));
typedef float f32x16 __attribute__((ext_vector_type(16)));

__device__ __forceinline__ u16 f2bf(float f) {
    unsigned int u = __float_as_uint(f);
    u += 0x7FFFu + ((u >> 16) & 1u);    // round-to-nearest-even
    return (u16)(u >> 16);
}
__device__ __forceinline__ unsigned int pack2(float a, float b) {
    return (unsigned int)f2bf(a) | ((unsigned int)f2bf(b) << 16);
}
__device__ __forceinline__ float fexp2(float x) {
#if __has_builtin(__builtin_amdgcn_exp2f)
    return __builtin_amdgcn_exp2f(x);   // raw v_exp_f32 (2^x)
#else
    return exp2f(x);
#endif
}
__device__ __forceinline__ unsigned int cvt_pk_bf16(float lo, float hi) {
    unsigned int r;
    asm("v_cvt_pk_bf16_f32 %0, %1, %2" : "=v"(r) : "v"(lo), "v"(hi));
    return r;
}
// v_permlane32_swap_b32 a, b:  a_hi <-> b_lo.
__device__ __forceinline__ void pl32_swap(unsigned int& a, unsigned int& b) {
    asm("v_permlane32_swap_b32 %0, %1" : "+v"(a), "+v"(b));
}

// ---------------------------------------------------------------------------
// Kernel 1: W [1024][128] fp32 -> WT [3][128][1024] bf16 (transposed).
// w_q gets (1/sqrt(128)) * log2(e) folded in, so softmax uses raw exp2.
// ---------------------------------------------------------------------------
__global__ __launch_bounds__(256) void prep_wt(const float* __restrict__ wq,
                                               const float* __restrict__ wk,
                                               const float* __restrict__ wv,
                                               u16* __restrict__ WT) {
    int id = blockIdx.x * 256 + threadIdx.x;
    if (id >= 3 * DK_ * F_) return;
    int m   = id / (DK_ * F_);
    int rem = id - m * (DK_ * F_);
    int c   = rem / F_;
    int k   = rem - c * F_;
    const float* w = (m == 0) ? wq : (m == 1) ? wk : wv;
    float v = w[k * DK_ + c];
    if (m == 0) v *= 0.12751741951f;   // (1/sqrt(128)) * log2(e)
    WT[id] = f2bf(v);
}

// ---------------------------------------------------------------------------
// Kernel 2: projection GEMM — R17 proj (proven mappings, BK=32, [.][40] LDS)
// with ONLY the T14 instruction reorder applied (R14-proven pattern):
//   prologue stage(0); loop { barrier -> issue step-k+1 loads (16 transient
//   regs) -> frag reads + 8 MFMA (loads fly) -> barrier -> cvt+write }.
// R19/R20's failures were new mappings/wider tiles (WRITE_SIZE 66MB scratch
// amplification) — none of that here.  Fragment-layout epilogue unchanged.
// ---------------------------------------------------------------------------
__global__ __launch_bounds__(256, 3) void proj(const float* __restrict__ xq,
                                               const float* __restrict__ xk,
                                               const float* __restrict__ xv,
                                               const u16* __restrict__ WT,
                                               u16* __restrict__ qfr,
                                               u16* __restrict__ kfr,
                                               u16* __restrict__ vfr) {
    const int mode = blockIdx.y;
    const float* X = (mode == 0) ? xq : (mode == 1) ? xk : xv;
    const u16*   W = WT + mode * (DK_ * F_);

    __shared__ u16 a_lds[64][40];    // identical to R17
    __shared__ u16 w_lds[128][40];

    const int t    = threadIdx.x;
    const int lane = t & 63;
    const int wv_  = t >> 6;
    const int l15  = lane & 15, l4 = lane >> 4;
    const int row0 = blockIdx.x * 64;

    // R17 staging mappings (unchanged):
    //   A: row ar = t>>2 (0..63), kk = (t&3)*8   -> 2 float4 loads, 1 int4 write
    //   W: col wc = t>>1 (0..127), wk_ = (t&1)*16 -> 2 int4 loads, 2 int4 writes
    const int ar = t >> 2, akk = (t & 3) * 8;
    const int wc = t >> 1, wkk = (t & 1) * 16;

    float4 f0, f1;            // 8 fp32 of X (transient across MFMA phase)
    int4   s0, s1;            // 16 bf16 of W

#define LOADS(k0)                                                               \
    {                                                                           \
        const float4* asrc = (const float4*)(X + (size_t)(row0 + ar) * F_ + (k0) + akk); \
        f0 = asrc[0]; f1 = asrc[1];                                             \
        const int4* wsrc = (const int4*)(W + (size_t)wc * F_ + (k0) + wkk);     \
        s0 = wsrc[0]; s1 = wsrc[1];                                             \
    }
#define WRITES()                                                                \
    {                                                                           \
        int4 o0;                                                                \
        o0.x = pack2(f0.x, f0.y); o0.y = pack2(f0.z, f0.w);                     \
        o0.z = pack2(f1.x, f1.y); o0.w = pack2(f1.z, f1.w);                     \
        *(int4*)&a_lds[ar][akk]     = o0;                                       \
        *(int4*)&w_lds[wc][wkk]     = s0;                                       \
        *(int4*)&w_lds[wc][wkk + 8] = s1;                                       \
    }

    f32x4 acc[8];
#pragma unroll
    for (int j = 0; j < 8; ++j) acc[j] = f32x4{0.f, 0.f, 0.f, 0.f};

    LOADS(0);
    WRITES();

    for (int k0 = 0; k0 < F_; k0 += 32) {
        __syncthreads();                       // staged step visible

        if (k0 + 32 < F_) LOADS(k0 + 32);      // next-step loads fly under MFMA

        short8 af = *(const short8*)&a_lds[wv_ * 16 + l15][l4 * 8];
        short8 bf[8];
#pragma unroll
        for (int ct = 0; ct < 8; ++ct)
            bf[ct] = *(const short8*)&w_lds[ct * 16 + l15][l4 * 8];

        if (mode < 2) {
#pragma unroll
            for (int ct = 0; ct < 8; ++ct)
                acc[ct] = __builtin_amdgcn_mfma_f32_16x16x32_bf16(af, bf[ct], acc[ct], 0, 0, 0);
        } else {
#pragma unroll
            for (int ct = 0; ct < 8; ++ct)
                acc[ct] = __builtin_amdgcn_mfma_f32_16x16x32_bf16(bf[ct], af, acc[ct], 0, 0, 0);
        }
        __syncthreads();                       // all reads done

        if (k0 + 32 < F_) WRITES();            // cvt + ds_write drain under next barrier
    }
#undef LOADS
#undef WRITES

    if (mode < 2) {
        u16* OUT = (mode == 0) ? qfr : kfr;
#pragma unroll
        for (int ct = 0; ct < 8; ++ct)
#pragma unroll
            for (int r = 0; r < 4; ++r) {
                int q = row0 + wv_ * 16 + l4 * 4 + r;     // row (q or kv)
                int d = ct * 16 + l15;                    // col
                int g = q >> 5, j = q & 31;
                int c = d >> 4, h2 = (d >> 3) & 1, e = d & 7;
                OUT[(((size_t)g * 8 + c) * 64 + h2 * 32 + j) * 8 + e] = f2bf(acc[ct][r]);
            }
    } else {
#pragma unroll
        for (int ct = 0; ct < 8; ++ct)
#pragma unroll
            for (int r = 0; r < 4; ++r) {
                int d = ct * 16 + l4 * 4 + r;             // C row = W col = d
                int m = row0 + wv_ * 16 + l15;            // C col = kv
                int g = m >> 5, ch = (m >> 4) & 1, h2 = (m >> 3) & 1, e = m & 7;
                int ct2 = d >> 5, l31 = d & 31;
                vfr[((((size_t)g * 4 + ct2) * 2 + ch) * 64 + h2 * 32 + l31) * 8 + e]
                    = f2bf(acc[ct][r]);
            }
    }
}

// ---------------------------------------------------------------------------
// Kernel 3: flash attention v7 (byte-identical to R17; 26us measured R18).
// ---------------------------------------------------------------------------
__global__ __launch_bounds__(512)
__attribute__((amdgpu_waves_per_eu(2)))
void attn(const u16* __restrict__ qfr,
          const u16* __restrict__ kfr,
          const u16* __restrict__ vfr,
          float* __restrict__ out) {
    __shared__ float ob[64][132];
    __shared__ float m_l[2][4][32], l_l[2][4][2][32], gm_l[2][32], gl_l[2][32];

    const int t      = threadIdx.x;
    const int lane   = t & 63;
    const int wv_    = t >> 6;              // 0..7
    const int q_sub  = wv_ & 1;
    const int kv_sub = wv_ >> 1;            // 0..3
    const int r31    = lane & 31;
    const int hi     = lane >> 5;

    const int b  = blockIdx.x & 7;
    const int qi = blockIdx.x >> 3;          // 0..31
    const int qrow0 = b * S_ + qi * 64;

    // Q fragments (coalesced: 1KB per instr)
    const size_t qg = (size_t)(b * 64 + qi * 2 + q_sub);
    short8 qf[8];
#pragma unroll
    for (int c = 0; c < 8; ++c)
        qf[c] = *(const short8*)(qfr + (qg * 8 + c) * 512 + lane * 8);

    f32x16 o4[4];
#pragma unroll
    for (int ct = 0; ct < 4; ++ct)
#pragma unroll
        for (int i = 0; i < 16; ++i) o4[ct][i] = 0.f;
    float mrun = -1.0e30f, lrun = 0.f;      // mrun cross-half uniform; lrun per-half

    // prologue: K fragments for kt=0
    short8 kf[8];
    {
        const size_t g0 = (size_t)(b * 64 + kv_sub);
#pragma unroll
        for (int c = 0; c < 8; ++c)
            kf[c] = *(const short8*)(kfr + (g0 * 8 + c) * 512 + lane * 8);
    }

    for (int kt = 0; kt < 16; ++kt) {
        const size_t g = (size_t)(b * 64 + kt * 4 + kv_sub);

        // ---- QK^T (own quarter), two independent 4-chains then add
        f32x16 sa, sb;
#pragma unroll
        for (int i = 0; i < 16; ++i) { sa[i] = 0.f; sb[i] = 0.f; }
#pragma unroll
        for (int c = 0; c < 4; ++c) {
            sa = __builtin_amdgcn_mfma_f32_32x32x16_bf16(kf[c],     qf[c],     sa, 0, 0, 0);
            sb = __builtin_amdgcn_mfma_f32_32x32x16_bf16(kf[c + 4], qf[c + 4], sb, 0, 0, 0);
        }
        f32x16 st;
#pragma unroll
        for (int i = 0; i < 16; ++i) st[i] = sa[i] + sb[i];

        // ---- V fragments issued now; land under softmax (coalesced dwordx4)
        short8 vf[4][2];
#pragma unroll
        for (int ct = 0; ct < 4; ++ct)
#pragma unroll
            for (int ch = 0; ch < 2; ++ch)
                vf[ct][ch] = *(const short8*)(vfr + (((g * 4 + ct) * 2 + ch) * 64 + lane) * 8);

        // ---- per-lane softmax (log2 units), cross-lane only in rare defer path
        float tm = st[0];
#pragma unroll
        for (int i = 1; i < 16; ++i) tm = fmaxf(tm, st[i]);
        if (__any(tm > mrun + 8.0f)) {
            tm = fmaxf(tm, __shfl_xor(tm, 32, 64));   // make mrun half-uniform
            float mn = fmaxf(mrun, tm);
            float fs = fexp2(mrun - mn);
            mrun = mn;
            lrun *= fs;
#pragma unroll
            for (int ct = 0; ct < 4; ++ct)
#pragma unroll
                for (int i = 0; i < 16; ++i) o4[ct][i] *= fs;
        }
        float s0 = 0.f, s1 = 0.f;
#pragma unroll
        for (int i = 0; i < 16; i += 2) {
            st[i]     = fexp2(st[i] - mrun);
            st[i + 1] = fexp2(st[i + 1] - mrun);
            s0 += st[i]; s1 += st[i + 1];
        }
        lrun += s0 + s1;

        // ---- P -> bf16 B-fragments via permlane32_swap
        short8 bp[2];
#pragma unroll
        for (int ch = 0; ch < 2; ++ch) {
            unsigned int A1 = cvt_pk_bf16(st[ch * 8 + 0], st[ch * 8 + 1]);
            unsigned int A2 = cvt_pk_bf16(st[ch * 8 + 2], st[ch * 8 + 3]);
            unsigned int A3 = cvt_pk_bf16(st[ch * 8 + 4], st[ch * 8 + 5]);
            unsigned int A4 = cvt_pk_bf16(st[ch * 8 + 6], st[ch * 8 + 7]);
            pl32_swap(A1, A3);
            pl32_swap(A2, A4);
            int4 w;
            w.x = (int)A1; w.y = (int)A2; w.z = (int)A3; w.w = (int)A4;
            bp[ch] = *(short8*)&w;
        }

        // ---- prefetch next K fragments (kf regs free); land under PV
        if (kt < 15) {
            const size_t gn = (size_t)(b * 64 + (kt + 1) * 4 + kv_sub);
#pragma unroll
            for (int c = 0; c < 8; ++c)
                kf[c] = *(const short8*)(kfr + (gn * 8 + c) * 512 + lane * 8);
        }

        // ---- PV: full d per wave, k-dim = this wave's 32-kv slice
#pragma unroll
        for (int ct = 0; ct < 4; ++ct) {
            o4[ct] = __builtin_amdgcn_mfma_f32_32x32x16_bf16(vf[ct][0], bp[0], o4[ct], 0, 0, 0);
            o4[ct] = __builtin_amdgcn_mfma_f32_32x32x16_bf16(vf[ct][1], bp[1], o4[ct], 0, 0, 0);
        }
    }

    // ---- epilogue: combine 4 kv_sub partials per q_sub ----
    __syncthreads();
    l_l[q_sub][kv_sub][hi][r31] = lrun;
    if (lane < 32) m_l[q_sub][kv_sub][r31] = mrun;
    __syncthreads();
    if (t < 64) {
        int qs = t >> 5, qq = t & 31;
        float gm = -1.0e30f;
#pragma unroll
        for (int ks = 0; ks < 4; ++ks) gm = fmaxf(gm, m_l[qs][ks][qq]);
        float gl = 0.f;
#pragma unroll
        for (int ks = 0; ks < 4; ++ks)
            gl += (l_l[qs][ks][0][qq] + l_l[qs][ks][1][qq]) * fexp2(m_l[qs][ks][qq] - gm);
        gm_l[qs][qq] = gm;
        gl_l[qs][qq] = gl;
    }
    __syncthreads();

    const float sc = fexp2(mrun - gm_l[q_sub][r31]);
    const int qrow = q_sub * 32 + r31;
    for (int rr = 0; rr < 4; ++rr) {
        if (kv_sub == rr) {
            if (rr == 0) {
#pragma unroll
                for (int ct = 0; ct < 4; ++ct)
#pragma unroll
                    for (int i = 0; i < 16; ++i) {
                        int d = ct * 32 + (i & 3) + 8 * (i >> 2) + 4 * hi;
                        ob[qrow][d] = o4[ct][i] * sc;
                    }
            } else {
#pragma unroll
                for (int ct = 0; ct < 4; ++ct)
#pragma unroll
                    for (int i = 0; i < 16; ++i) {
                        int d = ct * 32 + (i & 3) + 8 * (i >> 2) + 4 * hi;
                        ob[qrow][d] += o4[ct][i] * sc;
                    }
            }
        }
        __syncthreads();
    }

    // ---- final store: thread t -> row t>>3 (0..63), cols (t&7)*16..+16
    {
        int row = t >> 3, d0 = (t & 7) * 16;
        float inv = 1.0f / gl_l[row >> 5][row & 31];
        float* dst = out + (size_t)(qrow0 + row) * DK_ + d0;
#pragma unroll
        for (int j = 0; j < 16; j += 4) {
            float4 v;
            v.x = ob[row][d0 + j]     * inv;
            v.y = ob[row][d0 + j + 1] * inv;
            v.z = ob[row][d0 + j + 2] * inv;
            v.w = ob[row][d0 + j + 3] * inv;
            *(float4*)(dst + j) = v;
        }
    }
}

// ---------------------------------------------------------------------------
extern "C" void kernel_launch(void* const* d_in, const int* in_sizes, int n_in,
                              void* d_out, int out_size, void* d_ws, size_t ws_size,
                              hipStream_t stream) {
    const float* q  = (const float*)d_in[0];
    const float* k  = (const float*)d_in[1];
    const float* v  = (const float*)d_in[2];
    const float* wq = (const float*)d_in[3];
    const float* wk = (const float*)d_in[4];
    const float* wv = (const float*)d_in[5];
    float* out = (float*)d_out;

    char* ws = (char*)d_ws;
    u16* WT  = (u16*)ws;                                   // 786432 B
    u16* qfr = (u16*)(ws + 786432);                        // 4 MB (fragment layout)
    u16* kfr = (u16*)(ws + 786432 + 4194304);              // 4 MB
    u16* vfr = (u16*)(ws + 786432 + 2 * 4194304);          // 4 MB

    prep_wt<<<dim3(1536), dim3(256), 0, stream>>>(wq, wk, wv, WT);
    proj<<<dim3(256, 3), dim3(256), 0, stream>>>(q, k, v, WT, qfr, kfr, vfr);
    attn<<<dim3(256), dim3(512), 0, stream>>>(qfr, kfr, vfr, out);
}

// Round 22
// 72.165 us; speedup vs baseline: 1.3943x; 1.0292x over previous
//
#include <hip/hip_runtime.h>
#include <hip/hip_bf16.h>

#define B_ 8
#define S_ 2048
#define F_ 1024
#define DK_ 128
#define M_ (B_*S_)          // 16384

typedef unsigned short u16;
typedef short short8 __attribute__((ext_vector_type(8)));
typedef float f32x4 __attribute__((ext_vector_type(4)));
typedef float f32x16 __attribute__((ext_vector_type(16)));

__device__ __forceinline__ u16 f2bf(float f) {
    unsigned int u = __float_as_uint(f);
    u += 0x7FFFu + ((u >> 16) & 1u);    // round-to-nearest-even
    return (u16)(u >> 16);
}
__device__ __forceinline__ unsigned int pack2(float a, float b) {
    return (unsigned int)f2bf(a) | ((unsigned int)f2bf(b) << 16);
}
__device__ __forceinline__ float fexp2(float x) {
#if __has_builtin(__builtin_amdgcn_exp2f)
    return __builtin_amdgcn_exp2f(x);   // raw v_exp_f32 (2^x)
#else
    return exp2f(x);
#endif
}
__device__ __forceinline__ unsigned int cvt_pk_bf16(float lo, float hi) {
    unsigned int r;
    asm("v_cvt_pk_bf16_f32 %0, %1, %2" : "=v"(r) : "v"(lo), "v"(hi));
    return r;
}
// v_permlane32_swap_b32 a, b:  a_hi <-> b_lo.
__device__ __forceinline__ void pl32_swap(unsigned int& a, unsigned int& b) {
    asm("v_permlane32_swap_b32 %0, %1" : "+v"(a), "+v"(b));
}

// ---------------------------------------------------------------------------
// Kernel 1: W [1024][128] fp32 -> WT [3][128][1024] bf16 (transposed).
// w_q gets (1/sqrt(128)) * log2(e) folded in, so softmax uses raw exp2.
// ---------------------------------------------------------------------------
__global__ __launch_bounds__(256) void prep_wt(const float* __restrict__ wq,
                                               const float* __restrict__ wk,
                                               const float* __restrict__ wv,
                                               u16* __restrict__ WT) {
    int id = blockIdx.x * 256 + threadIdx.x;
    if (id >= 3 * DK_ * F_) return;
    int m   = id / (DK_ * F_);
    int rem = id - m * (DK_ * F_);
    int c   = rem / F_;
    int k   = rem - c * F_;
    const float* w = (m == 0) ? wq : (m == 1) ? wk : wv;
    float v = w[k * DK_ + c];
    if (m == 0) v *= 0.12751741951f;   // (1/sqrt(128)) * log2(e)
    WT[id] = f2bf(v);
}

// ---------------------------------------------------------------------------
// Kernel 2: projection GEMM — R17 mappings + LDS DOUBLE-BUFFER (1 barrier
// per K-step instead of 2).  R21 showed T14-reorder alone is useless while
// barrier2 still drains the writes; dbuf removes barrier2 structurally:
//   barrier -> LOADS(k+1) (fly under MFMA) -> frag reads + 8 MFMA from
//   buf[cur] -> WRITES(buf[cur^1]) -> loop.
// LDS 30.7KB (a 2x5KB + w 2x10KB) -> still 3 blocks/CU.  All mappings,
// staging widths, fragment epilogue identical to R17 (the three failed proj
// rewrites all changed mappings; this changes none).
// ---------------------------------------------------------------------------
__global__ __launch_bounds__(256, 3) void proj(const float* __restrict__ xq,
                                               const float* __restrict__ xk,
                                               const float* __restrict__ xv,
                                               const u16* __restrict__ WT,
                                               u16* __restrict__ qfr,
                                               u16* __restrict__ kfr,
                                               u16* __restrict__ vfr) {
    const int mode = blockIdx.y;
    const float* X = (mode == 0) ? xq : (mode == 1) ? xk : xv;
    const u16*   W = WT + mode * (DK_ * F_);

    __shared__ u16 a_lds[2][64][40];
    __shared__ u16 w_lds[2][128][40];

    const int t    = threadIdx.x;
    const int lane = t & 63;
    const int wv_  = t >> 6;
    const int l15  = lane & 15, l4 = lane >> 4;
    const int row0 = blockIdx.x * 64;

    // R17 staging mappings (unchanged):
    //   A: row ar = t>>2 (0..63), kk = (t&3)*8   -> 2 float4 loads, 1 int4 write
    //   W: col wc = t>>1 (0..127), wkk = (t&1)*16 -> 2 int4 loads, 2 int4 writes
    const int ar = t >> 2, akk = (t & 3) * 8;
    const int wc = t >> 1, wkk = (t & 1) * 16;

    float4 f0, f1;            // 8 fp32 of X (transient across MFMA phase)
    int4   s0, s1;            // 16 bf16 of W

#define LOADS(k0)                                                               \
    {                                                                           \
        const float4* asrc = (const float4*)(X + (size_t)(row0 + ar) * F_ + (k0) + akk); \
        f0 = asrc[0]; f1 = asrc[1];                                             \
        const int4* wsrc = (const int4*)(W + (size_t)wc * F_ + (k0) + wkk);     \
        s0 = wsrc[0]; s1 = wsrc[1];                                             \
    }
#define WRITES(nb)                                                              \
    {                                                                           \
        int4 o0;                                                                \
        o0.x = pack2(f0.x, f0.y); o0.y = pack2(f0.z, f0.w);                     \
        o0.z = pack2(f1.x, f1.y); o0.w = pack2(f1.z, f1.w);                     \
        *(int4*)&a_lds[nb][ar][akk]     = o0;                                   \
        *(int4*)&w_lds[nb][wc][wkk]     = s0;                                   \
        *(int4*)&w_lds[nb][wc][wkk + 8] = s1;                                   \
    }

    f32x4 acc[8];
#pragma unroll
    for (int j = 0; j < 8; ++j) acc[j] = f32x4{0.f, 0.f, 0.f, 0.f};

    LOADS(0);
    WRITES(0);
    int cur = 0;

    for (int k0 = 0; k0 < F_; k0 += 32) {
        __syncthreads();                       // buf[cur] fully written

        if (k0 + 32 < F_) LOADS(k0 + 32);      // next-step loads fly under MFMA

        short8 af = *(const short8*)&a_lds[cur][wv_ * 16 + l15][l4 * 8];
        short8 bf[8];
#pragma unroll
        for (int ct = 0; ct < 8; ++ct)
            bf[ct] = *(const short8*)&w_lds[cur][ct * 16 + l15][l4 * 8];

        if (mode < 2) {
#pragma unroll
            for (int ct = 0; ct < 8; ++ct)
                acc[ct] = __builtin_amdgcn_mfma_f32_16x16x32_bf16(af, bf[ct], acc[ct], 0, 0, 0);
        } else {
#pragma unroll
            for (int ct = 0; ct < 8; ++ct)
                acc[ct] = __builtin_amdgcn_mfma_f32_16x16x32_bf16(bf[ct], af, acc[ct], 0, 0, 0);
        }

        if (k0 + 32 < F_) WRITES(cur ^ 1);     // other buffer: no race with reads
        cur ^= 1;
    }
#undef LOADS
#undef WRITES

    if (mode < 2) {
        u16* OUT = (mode == 0) ? qfr : kfr;
#pragma unroll
        for (int ct = 0; ct < 8; ++ct)
#pragma unroll
            for (int r = 0; r < 4; ++r) {
                int q = row0 + wv_ * 16 + l4 * 4 + r;     // row (q or kv)
                int d = ct * 16 + l15;                    // col
                int g = q >> 5, j = q & 31;
                int c = d >> 4, h2 = (d >> 3) & 1, e = d & 7;
                OUT[(((size_t)g * 8 + c) * 64 + h2 * 32 + j) * 8 + e] = f2bf(acc[ct][r]);
            }
    } else {
#pragma unroll
        for (int ct = 0; ct < 8; ++ct)
#pragma unroll
            for (int r = 0; r < 4; ++r) {
                int d = ct * 16 + l4 * 4 + r;             // C row = W col = d
                int m = row0 + wv_ * 16 + l15;            // C col = kv
                int g = m >> 5, ch = (m >> 4) & 1, h2 = (m >> 3) & 1, e = m & 7;
                int ct2 = d >> 5, l31 = d & 31;
                vfr[((((size_t)g * 4 + ct2) * 2 + ch) * 64 + h2 * 32 + l31) * 8 + e]
                    = f2bf(acc[ct][r]);
            }
    }
}

// ---------------------------------------------------------------------------
// Kernel 3: flash attention v7 (byte-identical to R17; 26us measured R18).
// ---------------------------------------------------------------------------
__global__ __launch_bounds__(512)
__attribute__((amdgpu_waves_per_eu(2)))
void attn(const u16* __restrict__ qfr,
          const u16* __restrict__ kfr,
          const u16* __restrict__ vfr,
          float* __restrict__ out) {
    __shared__ float ob[64][132];
    __shared__ float m_l[2][4][32], l_l[2][4][2][32], gm_l[2][32], gl_l[2][32];

    const int t      = threadIdx.x;
    const int lane   = t & 63;
    const int wv_    = t >> 6;              // 0..7
    const int q_sub  = wv_ & 1;
    const int kv_sub = wv_ >> 1;            // 0..3
    const int r31    = lane & 31;
    const int hi     = lane >> 5;

    const int b  = blockIdx.x & 7;
    const int qi = blockIdx.x >> 3;          // 0..31
    const int qrow0 = b * S_ + qi * 64;

    // Q fragments (coalesced: 1KB per instr)
    const size_t qg = (size_t)(b * 64 + qi * 2 + q_sub);
    short8 qf[8];
#pragma unroll
    for (int c = 0; c < 8; ++c)
        qf[c] = *(const short8*)(qfr + (qg * 8 + c) * 512 + lane * 8);

    f32x16 o4[4];
#pragma unroll
    for (int ct = 0; ct < 4; ++ct)
#pragma unroll
        for (int i = 0; i < 16; ++i) o4[ct][i] = 0.f;
    float mrun = -1.0e30f, lrun = 0.f;      // mrun cross-half uniform; lrun per-half

    // prologue: K fragments for kt=0
    short8 kf[8];
    {
        const size_t g0 = (size_t)(b * 64 + kv_sub);
#pragma unroll
        for (int c = 0; c < 8; ++c)
            kf[c] = *(const short8*)(kfr + (g0 * 8 + c) * 512 + lane * 8);
    }

    for (int kt = 0; kt < 16; ++kt) {
        const size_t g = (size_t)(b * 64 + kt * 4 + kv_sub);

        // ---- QK^T (own quarter), two independent 4-chains then add
        f32x16 sa, sb;
#pragma unroll
        for (int i = 0; i < 16; ++i) { sa[i] = 0.f; sb[i] = 0.f; }
#pragma unroll
        for (int c = 0; c < 4; ++c) {
            sa = __builtin_amdgcn_mfma_f32_32x32x16_bf16(kf[c],     qf[c],     sa, 0, 0, 0);
            sb = __builtin_amdgcn_mfma_f32_32x32x16_bf16(kf[c + 4], qf[c + 4], sb, 0, 0, 0);
        }
        f32x16 st;
#pragma unroll
        for (int i = 0; i < 16; ++i) st[i] = sa[i] + sb[i];

        // ---- V fragments issued now; land under softmax (coalesced dwordx4)
        short8 vf[4][2];
#pragma unroll
        for (int ct = 0; ct < 4; ++ct)
#pragma unroll
            for (int ch = 0; ch < 2; ++ch)
                vf[ct][ch] = *(const short8*)(vfr + (((g * 4 + ct) * 2 + ch) * 64 + lane) * 8);

        // ---- per-lane softmax (log2 units), cross-lane only in rare defer path
        float tm = st[0];
#pragma unroll
        for (int i = 1; i < 16; ++i) tm = fmaxf(tm, st[i]);
        if (__any(tm > mrun + 8.0f)) {
            tm = fmaxf(tm, __shfl_xor(tm, 32, 64));   // make mrun half-uniform
            float mn = fmaxf(mrun, tm);
            float fs = fexp2(mrun - mn);
            mrun = mn;
            lrun *= fs;
#pragma unroll
            for (int ct = 0; ct < 4; ++ct)
#pragma unroll
                for (int i = 0; i < 16; ++i) o4[ct][i] *= fs;
        }
        float s0 = 0.f, s1 = 0.f;
#pragma unroll
        for (int i = 0; i < 16; i += 2) {
            st[i]     = fexp2(st[i] - mrun);
            st[i + 1] = fexp2(st[i + 1] - mrun);
            s0 += st[i]; s1 += st[i + 1];
        }
        lrun += s0 + s1;

        // ---- P -> bf16 B-fragments via permlane32_swap
        short8 bp[2];
#pragma unroll
        for (int ch = 0; ch < 2; ++ch) {
            unsigned int A1 = cvt_pk_bf16(st[ch * 8 + 0], st[ch * 8 + 1]);
            unsigned int A2 = cvt_pk_bf16(st[ch * 8 + 2], st[ch * 8 + 3]);
            unsigned int A3 = cvt_pk_bf16(st[ch * 8 + 4], st[ch * 8 + 5]);
            unsigned int A4 = cvt_pk_bf16(st[ch * 8 + 6], st[ch * 8 + 7]);
            pl32_swap(A1, A3);
            pl32_swap(A2, A4);
            int4 w;
            w.x = (int)A1; w.y = (int)A2; w.z = (int)A3; w.w = (int)A4;
            bp[ch] = *(short8*)&w;
        }

        // ---- prefetch next K fragments (kf regs free); land under PV
        if (kt < 15) {
            const size_t gn = (size_t)(b * 64 + (kt + 1) * 4 + kv_sub);
#pragma unroll
            for (int c = 0; c < 8; ++c)
                kf[c] = *(const short8*)(kfr + (gn * 8 + c) * 512 + lane * 8);
        }

        // ---- PV: full d per wave, k-dim = this wave's 32-kv slice
#pragma unroll
        for (int ct = 0; ct < 4; ++ct) {
            o4[ct] = __builtin_amdgcn_mfma_f32_32x32x16_bf16(vf[ct][0], bp[0], o4[ct], 0, 0, 0);
            o4[ct] = __builtin_amdgcn_mfma_f32_32x32x16_bf16(vf[ct][1], bp[1], o4[ct], 0, 0, 0);
        }
    }

    // ---- epilogue: combine 4 kv_sub partials per q_sub ----
    __syncthreads();
    l_l[q_sub][kv_sub][hi][r31] = lrun;
    if (lane < 32) m_l[q_sub][kv_sub][r31] = mrun;
    __syncthreads();
    if (t < 64) {
        int qs = t >> 5, qq = t & 31;
        float gm = -1.0e30f;
#pragma unroll
        for (int ks = 0; ks < 4; ++ks) gm = fmaxf(gm, m_l[qs][ks][qq]);
        float gl = 0.f;
#pragma unroll
        for (int ks = 0; ks < 4; ++ks)
            gl += (l_l[qs][ks][0][qq] + l_l[qs][ks][1][qq]) * fexp2(m_l[qs][ks][qq] - gm);
        gm_l[qs][qq] = gm;
        gl_l[qs][qq] = gl;
    }
    __syncthreads();

    const float sc = fexp2(mrun - gm_l[q_sub][r31]);
    const int qrow = q_sub * 32 + r31;
    for (int rr = 0; rr < 4; ++rr) {
        if (kv_sub == rr) {
            if (rr == 0) {
#pragma unroll
                for (int ct = 0; ct < 4; ++ct)
#pragma unroll
                    for (int i = 0; i < 16; ++i) {
                        int d = ct * 32 + (i & 3) + 8 * (i >> 2) + 4 * hi;
                        ob[qrow][d] = o4[ct][i] * sc;
                    }
            } else {
#pragma unroll
                for (int ct = 0; ct < 4; ++ct)
#pragma unroll
                    for (int i = 0; i < 16; ++i) {
                        int d = ct * 32 + (i & 3) + 8 * (i >> 2) + 4 * hi;
                        ob[qrow][d] += o4[ct][i] * sc;
                    }
            }
        }
        __syncthreads();
    }

    // ---- final store: thread t -> row t>>3 (0..63), cols (t&7)*16..+16
    {
        int row = t >> 3, d0 = (t & 7) * 16;
        float inv = 1.0f / gl_l[row >> 5][row & 31];
        float* dst = out + (size_t)(qrow0 + row) * DK_ + d0;
#pragma unroll
        for (int j = 0; j < 16; j += 4) {
            float4 v;
            v.x = ob[row][d0 + j]     * inv;
            v.y = ob[row][d0 + j + 1] * inv;
            v.z = ob[row][d0 + j + 2] * inv;
            v.w = ob[row][d0 + j + 3] * inv;
            *(float4*)(dst + j) = v;
        }
    }
}

// ---------------------------------------------------------------------------
extern "C" void kernel_launch(void* const* d_in, const int* in_sizes, int n_in,
                              void* d_out, int out_size, void* d_ws, size_t ws_size,
                              hipStream_t stream) {
    const float* q  = (const float*)d_in[0];
    const float* k  = (const float*)d_in[1];
    const float* v  = (const float*)d_in[2];
    const float* wq = (const float*)d_in[3];
    const float* wk = (const float*)d_in[4];
    const float* wv = (const float*)d_in[5];
    float* out = (float*)d_out;

    char* ws = (char*)d_ws;
    u16* WT  = (u16*)ws;                                   // 786432 B
    u16* qfr = (u16*)(ws + 786432);                        // 4 MB (fragment layout)
    u16* kfr = (u16*)(ws + 786432 + 4194304);              // 4 MB
    u16* vfr = (u16*)(ws + 786432 + 2 * 4194304);          // 4 MB

    prep_wt<<<dim3(1536), dim3(256), 0, stream>>>(wq, wk, wv, WT);
    proj<<<dim3(256, 3), dim3(256), 0, stream>>>(q, k, v, WT, qfr, kfr, vfr);
    attn<<<dim3(256), dim3(512), 0, stream>>>(qfr, kfr, vfr, out);
}

// Round 23
// 70.792 us; speedup vs baseline: 1.4213x; 1.0194x over previous
//
#include <hip/hip_runtime.h>
#include <hip/hip_bf16.h>

#define B_ 8
#define S_ 2048
#define F_ 1024
#define DK_ 128
#define M_ (B_*S_)          // 16384

typedef unsigned short u16;
typedef short short8 __attribute__((ext_vector_type(8)));
typedef float f32x4 __attribute__((ext_vector_type(4)));
typedef float f32x16 __attribute__((ext_vector_type(16)));

__device__ __forceinline__ u16 f2bf(float f) {
    unsigned int u = __float_as_uint(f);
    u += 0x7FFFu + ((u >> 16) & 1u);    // round-to-nearest-even
    return (u16)(u >> 16);
}
__device__ __forceinline__ unsigned int pack2(float a, float b) {
    return (unsigned int)f2bf(a) | ((unsigned int)f2bf(b) << 16);
}
__device__ __forceinline__ float fexp2(float x) {
#if __has_builtin(__builtin_amdgcn_exp2f)
    return __builtin_amdgcn_exp2f(x);   // raw v_exp_f32 (2^x)
#else
    return exp2f(x);
#endif
}
__device__ __forceinline__ unsigned int cvt_pk_bf16(float lo, float hi) {
    unsigned int r;
    asm("v_cvt_pk_bf16_f32 %0, %1, %2" : "=v"(r) : "v"(lo), "v"(hi));
    return r;
}
// v_permlane32_swap_b32 a, b:  a_hi <-> b_lo.
__device__ __forceinline__ void pl32_swap(unsigned int& a, unsigned int& b) {
    asm("v_permlane32_swap_b32 %0, %1" : "+v"(a), "+v"(b));
}

// ---------------------------------------------------------------------------
// Kernel 1: W [1024][128] fp32 -> WT [3][128][1024] bf16 (transposed).
// w_q gets (1/sqrt(128)) * log2(e) folded in, so softmax uses raw exp2.
// ---------------------------------------------------------------------------
__global__ __launch_bounds__(256) void prep_wt(const float* __restrict__ wq,
                                               const float* __restrict__ wk,
                                               const float* __restrict__ wv,
                                               u16* __restrict__ WT) {
    int id = blockIdx.x * 256 + threadIdx.x;
    if (id >= 3 * DK_ * F_) return;
    int m   = id / (DK_ * F_);
    int rem = id - m * (DK_ * F_);
    int c   = rem / F_;
    int k   = rem - c * F_;
    const float* w = (m == 0) ? wq : (m == 1) ? wk : wv;
    float v = w[k * DK_ + c];
    if (m == 0) v *= 0.12751741951f;   // (1/sqrt(128)) * log2(e)
    WT[id] = f2bf(v);
}

// ---------------------------------------------------------------------------
// Kernel 2: projection GEMM — R17 version verbatim (best measured: proj ~40us,
// total 70.6).  BK=32, [.][40] LDS, 2 barriers/step; five structural variants
// (split dispatch / BK=128 / BK=64+T14 / T14-reorder / dbuf) all landed >= this,
// because the kernel is X-stream BW-bound (192MB fp32 at ~4.8 TB/s effective).
// Fragment-layout epilogue feeds attn's coalesced no-LDS loop.
// ---------------------------------------------------------------------------
__global__ __launch_bounds__(256, 3) void proj(const float* __restrict__ xq,
                                               const float* __restrict__ xk,
                                               const float* __restrict__ xv,
                                               const u16* __restrict__ WT,
                                               u16* __restrict__ qfr,
                                               u16* __restrict__ kfr,
                                               u16* __restrict__ vfr) {
    const int mode = blockIdx.y;
    const float* X = (mode == 0) ? xq : (mode == 1) ? xk : xv;
    const u16*   W = WT + mode * (DK_ * F_);

    __shared__ u16 a_lds[64][40];
    __shared__ u16 w_lds[128][40];

    const int t    = threadIdx.x;
    const int lane = t & 63;
    const int wv_  = t >> 6;
    const int l15  = lane & 15, l4 = lane >> 4;
    const int row0 = blockIdx.x * 64;

    f32x4 acc[8];
#pragma unroll
    for (int j = 0; j < 8; ++j) acc[j] = f32x4{0.f, 0.f, 0.f, 0.f};

    for (int k0 = 0; k0 < F_; k0 += 32) {
        {
            int r = t >> 2, kk = (t & 3) * 8;
            const float4* src = (const float4*)(X + (size_t)(row0 + r) * F_ + k0 + kk);
            float4 f0 = src[0], f1 = src[1];
            int4 o0;
            o0.x = pack2(f0.x, f0.y); o0.y = pack2(f0.z, f0.w);
            o0.z = pack2(f1.x, f1.y); o0.w = pack2(f1.z, f1.w);
            *(int4*)&a_lds[r][kk] = o0;
        }
        {
            int c = t >> 1, kk = (t & 1) * 16;
            const int4* src = (const int4*)(W + (size_t)c * F_ + k0 + kk);
            *(int4*)&w_lds[c][kk]     = src[0];
            *(int4*)&w_lds[c][kk + 8] = src[1];
        }
        __syncthreads();

        short8 af = *(const short8*)&a_lds[wv_ * 16 + l15][l4 * 8];
        short8 bf[8];
#pragma unroll
        for (int ct = 0; ct < 8; ++ct)
            bf[ct] = *(const short8*)&w_lds[ct * 16 + l15][l4 * 8];

        if (mode < 2) {
#pragma unroll
            for (int ct = 0; ct < 8; ++ct)
                acc[ct] = __builtin_amdgcn_mfma_f32_16x16x32_bf16(af, bf[ct], acc[ct], 0, 0, 0);
        } else {
#pragma unroll
            for (int ct = 0; ct < 8; ++ct)
                acc[ct] = __builtin_amdgcn_mfma_f32_16x16x32_bf16(bf[ct], af, acc[ct], 0, 0, 0);
        }
        __syncthreads();
    }

    if (mode < 2) {
        u16* OUT = (mode == 0) ? qfr : kfr;
#pragma unroll
        for (int ct = 0; ct < 8; ++ct)
#pragma unroll
            for (int r = 0; r < 4; ++r) {
                int q = row0 + wv_ * 16 + l4 * 4 + r;     // row (q or kv)
                int d = ct * 16 + l15;                    // col
                int g = q >> 5, j = q & 31;
                int c = d >> 4, h2 = (d >> 3) & 1, e = d & 7;
                OUT[(((size_t)g * 8 + c) * 64 + h2 * 32 + j) * 8 + e] = f2bf(acc[ct][r]);
            }
    } else {
#pragma unroll
        for (int ct = 0; ct < 8; ++ct)
#pragma unroll
            for (int r = 0; r < 4; ++r) {
                int d = ct * 16 + l4 * 4 + r;             // C row = W col = d
                int m = row0 + wv_ * 16 + l15;            // C col = kv
                int g = m >> 5, ch = (m >> 4) & 1, h2 = (m >> 3) & 1, e = m & 7;
                int ct2 = d >> 5, l31 = d & 31;
                vfr[((((size_t)g * 4 + ct2) * 2 + ch) * 64 + h2 * 32 + l31) * 8 + e]
                    = f2bf(acc[ct][r]);
            }
    }
}

// ---------------------------------------------------------------------------
// Kernel 3: flash attention v7 (R17 verbatim; 26us measured via R18's
// double-dispatch).  No LDS in loop, fragment-order coalesced L2 loads,
// zero in-loop barriers, swapped-QK^T in-register softmax.
// ---------------------------------------------------------------------------
__global__ __launch_bounds__(512)
__attribute__((amdgpu_waves_per_eu(2)))
void attn(const u16* __restrict__ qfr,
          const u16* __restrict__ kfr,
          const u16* __restrict__ vfr,
          float* __restrict__ out) {
    __shared__ float ob[64][132];
    __shared__ float m_l[2][4][32], l_l[2][4][2][32], gm_l[2][32], gl_l[2][32];

    const int t      = threadIdx.x;
    const int lane   = t & 63;
    const int wv_    = t >> 6;              // 0..7
    const int q_sub  = wv_ & 1;
    const int kv_sub = wv_ >> 1;            // 0..3
    const int r31    = lane & 31;
    const int hi     = lane >> 5;

    const int b  = blockIdx.x & 7;
    const int qi = blockIdx.x >> 3;          // 0..31
    const int qrow0 = b * S_ + qi * 64;

    // Q fragments (coalesced: 1KB per instr)
    const size_t qg = (size_t)(b * 64 + qi * 2 + q_sub);
    short8 qf[8];
#pragma unroll
    for (int c = 0; c < 8; ++c)
        qf[c] = *(const short8*)(qfr + (qg * 8 + c) * 512 + lane * 8);

    f32x16 o4[4];
#pragma unroll
    for (int ct = 0; ct < 4; ++ct)
#pragma unroll
        for (int i = 0; i < 16; ++i) o4[ct][i] = 0.f;
    float mrun = -1.0e30f, lrun = 0.f;      // mrun cross-half uniform; lrun per-half

    // prologue: K fragments for kt=0
    short8 kf[8];
    {
        const size_t g0 = (size_t)(b * 64 + kv_sub);
#pragma unroll
        for (int c = 0; c < 8; ++c)
            kf[c] = *(const short8*)(kfr + (g0 * 8 + c) * 512 + lane * 8);
    }

    for (int kt = 0; kt < 16; ++kt) {
        const size_t g = (size_t)(b * 64 + kt * 4 + kv_sub);

        // ---- QK^T (own quarter), two independent 4-chains then add
        f32x16 sa, sb;
#pragma unroll
        for (int i = 0; i < 16; ++i) { sa[i] = 0.f; sb[i] = 0.f; }
#pragma unroll
        for (int c = 0; c < 4; ++c) {
            sa = __builtin_amdgcn_mfma_f32_32x32x16_bf16(kf[c],     qf[c],     sa, 0, 0, 0);
            sb = __builtin_amdgcn_mfma_f32_32x32x16_bf16(kf[c + 4], qf[c + 4], sb, 0, 0, 0);
        }
        f32x16 st;
#pragma unroll
        for (int i = 0; i < 16; ++i) st[i] = sa[i] + sb[i];

        // ---- V fragments issued now; land under softmax (coalesced dwordx4)
        short8 vf[4][2];
#pragma unroll
        for (int ct = 0; ct < 4; ++ct)
#pragma unroll
            for (int ch = 0; ch < 2; ++ch)
                vf[ct][ch] = *(const short8*)(vfr + (((g * 4 + ct) * 2 + ch) * 64 + lane) * 8);

        // ---- per-lane softmax (log2 units), cross-lane only in rare defer path
        float tm = st[0];
#pragma unroll
        for (int i = 1; i < 16; ++i) tm = fmaxf(tm, st[i]);
        if (__any(tm > mrun + 8.0f)) {
            tm = fmaxf(tm, __shfl_xor(tm, 32, 64));   // make mrun half-uniform
            float mn = fmaxf(mrun, tm);
            float fs = fexp2(mrun - mn);
            mrun = mn;
            lrun *= fs;
#pragma unroll
            for (int ct = 0; ct < 4; ++ct)
#pragma unroll
                for (int i = 0; i < 16; ++i) o4[ct][i] *= fs;
        }
        float s0 = 0.f, s1 = 0.f;
#pragma unroll
        for (int i = 0; i < 16; i += 2) {
            st[i]     = fexp2(st[i] - mrun);
            st[i + 1] = fexp2(st[i + 1] - mrun);
            s0 += st[i]; s1 += st[i + 1];
        }
        lrun += s0 + s1;

        // ---- P -> bf16 B-fragments via permlane32_swap
        short8 bp[2];
#pragma unroll
        for (int ch = 0; ch < 2; ++ch) {
            unsigned int A1 = cvt_pk_bf16(st[ch * 8 + 0], st[ch * 8 + 1]);
            unsigned int A2 = cvt_pk_bf16(st[ch * 8 + 2], st[ch * 8 + 3]);
            unsigned int A3 = cvt_pk_bf16(st[ch * 8 + 4], st[ch * 8 + 5]);
            unsigned int A4 = cvt_pk_bf16(st[ch * 8 + 6], st[ch * 8 + 7]);
            pl32_swap(A1, A3);
            pl32_swap(A2, A4);
            int4 w;
            w.x = (int)A1; w.y = (int)A2; w.z = (int)A3; w.w = (int)A4;
            bp[ch] = *(short8*)&w;
        }

        // ---- prefetch next K fragments (kf regs free); land under PV
        if (kt < 15) {
            const size_t gn = (size_t)(b * 64 + (kt + 1) * 4 + kv_sub);
#pragma unroll
            for (int c = 0; c < 8; ++c)
                kf[c] = *(const short8*)(kfr + (gn * 8 + c) * 512 + lane * 8);
        }

        // ---- PV: full d per wave, k-dim = this wave's 32-kv slice
#pragma unroll
        for (int ct = 0; ct < 4; ++ct) {
            o4[ct] = __builtin_amdgcn_mfma_f32_32x32x16_bf16(vf[ct][0], bp[0], o4[ct], 0, 0, 0);
            o4[ct] = __builtin_amdgcn_mfma_f32_32x32x16_bf16(vf[ct][1], bp[1], o4[ct], 0, 0, 0);
        }
    }

    // ---- epilogue: combine 4 kv_sub partials per q_sub ----
    __syncthreads();
    l_l[q_sub][kv_sub][hi][r31] = lrun;
    if (lane < 32) m_l[q_sub][kv_sub][r31] = mrun;
    __syncthreads();
    if (t < 64) {
        int qs = t >> 5, qq = t & 31;
        float gm = -1.0e30f;
#pragma unroll
        for (int ks = 0; ks < 4; ++ks) gm = fmaxf(gm, m_l[qs][ks][qq]);
        float gl = 0.f;
#pragma unroll
        for (int ks = 0; ks < 4; ++ks)
            gl += (l_l[qs][ks][0][qq] + l_l[qs][ks][1][qq]) * fexp2(m_l[qs][ks][qq] - gm);
        gm_l[qs][qq] = gm;
        gl_l[qs][qq] = gl;
    }
    __syncthreads();

    const float sc = fexp2(mrun - gm_l[q_sub][r31]);
    const int qrow = q_sub * 32 + r31;
    for (int rr = 0; rr < 4; ++rr) {
        if (kv_sub == rr) {
            if (rr == 0) {
#pragma unroll
                for (int ct = 0; ct < 4; ++ct)
#pragma unroll
                    for (int i = 0; i < 16; ++i) {
                        int d = ct * 32 + (i & 3) + 8 * (i >> 2) + 4 * hi;
                        ob[qrow][d] = o4[ct][i] * sc;
                    }
            } else {
#pragma unroll
                for (int ct = 0; ct < 4; ++ct)
#pragma unroll
                    for (int i = 0; i < 16; ++i) {
                        int d = ct * 32 + (i & 3) + 8 * (i >> 2) + 4 * hi;
                        ob[qrow][d] += o4[ct][i] * sc;
                    }
            }
        }
        __syncthreads();
    }

    // ---- final store: thread t -> row t>>3 (0..63), cols (t&7)*16..+16
    {
        int row = t >> 3, d0 = (t & 7) * 16;
        float inv = 1.0f / gl_l[row >> 5][row & 31];
        float* dst = out + (size_t)(qrow0 + row) * DK_ + d0;
#pragma unroll
        for (int j = 0; j < 16; j += 4) {
            float4 v;
            v.x = ob[row][d0 + j]     * inv;
            v.y = ob[row][d0 + j + 1] * inv;
            v.z = ob[row][d0 + j + 2] * inv;
            v.w = ob[row][d0 + j + 3] * inv;
            *(float4*)(dst + j) = v;
        }
    }
}

// ---------------------------------------------------------------------------
extern "C" void kernel_launch(void* const* d_in, const int* in_sizes, int n_in,
                              void* d_out, int out_size, void* d_ws, size_t ws_size,
                              hipStream_t stream) {
    const float* q  = (const float*)d_in[0];
    const float* k  = (const float*)d_in[1];
    const float* v  = (const float*)d_in[2];
    const float* wq = (const float*)d_in[3];
    const float* wk = (const float*)d_in[4];
    const float* wv = (const float*)d_in[5];
    float* out = (float*)d_out;

    char* ws = (char*)d_ws;
    u16* WT  = (u16*)ws;                                   // 786432 B
    u16* qfr = (u16*)(ws + 786432);                        // 4 MB (fragment layout)
    u16* kfr = (u16*)(ws + 786432 + 4194304);              // 4 MB
    u16* vfr = (u16*)(ws + 786432 + 2 * 4194304);          // 4 MB

    prep_wt<<<dim3(1536), dim3(256), 0, stream>>>(wq, wk, wv, WT);
    proj<<<dim3(256, 3), dim3(256), 0, stream>>>(q, k, v, WT, qfr, kfr, vfr);
    attn<<<dim3(256), dim3(512), 0, stream>>>(qfr, kfr, vfr, out);
}